// Round 3
// baseline (427.785 us; speedup 1.0000x reference)
//
#include <hip/hip_runtime.h>
#include <cstddef>
#include <cstdint>

#define LPIX 576
#define CCH  2048
#define NB   4

typedef __attribute__((ext_vector_type(8))) short short8;
typedef __attribute__((ext_vector_type(16))) float f32x16;
typedef __attribute__((ext_vector_type(4))) unsigned short u16x4;

__device__ __forceinline__ unsigned short f2bf(float f) {
    uint32_t u = __builtin_bit_cast(uint32_t, f);
    u += 0x7fff + ((u >> 16) & 1);          // round-to-nearest-even
    return (unsigned short)(u >> 16);
}
__device__ __forceinline__ float bf2f(unsigned short s) {
    return __builtin_bit_cast(float, (uint32_t)s << 16);
}

__device__ __forceinline__ void gload_lds16(const void* g, void* l) {
    __builtin_amdgcn_global_load_lds((const __attribute__((address_space(1))) void*)g,
                                     (__attribute__((address_space(3))) void*)l, 16, 0, 0);
}

// C/D layout of 32x32 MFMA: col = lane&31, row = (r&3) + 8*(r>>2) + 4*(lane>>5)
#define ROW32(r, h) (((r) & 3) + 8 * ((r) >> 2) + 4 * (h))

// ---------------- MFMA K-loop: 32x32x16, 4 waves (2x2), DOUBLE-buffered ----------------
// Per step: (1) ds_read ALL fragments of cur buffer into regs (program-order FIRST, so no
// vmem wait can precede them — prev step's __syncthreads already drained vmcnt);
// (2) issue next-tile global_load_lds into the other buffer; (3) MFMA; (4) one
// __syncthreads. The end-of-step implicit vmcnt(0) drain now waits on loads issued
// ~400-500 cy earlier (covered by LDS reads + MFMA) instead of stalling cold.
// Sync semantics unchanged vs the passing round-2 kernel (every cross-wave LDS
// write->read is still separated by a full-drain barrier).
template<int BM, int BN, int FM, int FN>
__device__ __forceinline__ void mm32_core(
    const short* __restrict__ Ab, int lda,
    const short* __restrict__ Bb, int ldb,
    int k0, int kend, short* As, short* Bs,   // As: 2*BM*64 shorts, Bs: 2*BN*64
    int m0, int n0, f32x16 (&acc)[FM][FN])
{
    constexpr int NA  = BM * 8 / 256;     // A 16B-chunks per thread per 64k step
    constexpr int NBC = BN * 8 / 256;
    constexpr int ASZ = BM * 64;          // shorts per A buffer
    constexpr int BSZ = BN * 64;
    const int tid  = threadIdx.x;
    const int lane = tid & 63;
    const int w    = tid >> 6;            // 0..3
    const int wr   = w & 1, wc = w >> 1;  // 2x2 wave grid
    const int u31  = lane & 31;
    const int h    = lane >> 5;

    const short* Aptr[NA]; short* Alds[NA];
    #pragma unroll
    for (int t = 0; t < NA; ++t) {
        const int c = t * 256 + tid;
        const int row = c >> 3, sl = c & 7;
        Aptr[t] = Ab + (size_t)(m0 + row) * lda + ((sl ^ (row & 7)) * 8);  // pre-swizzled src
        Alds[t] = As + c * 8;                                             // linear dest
    }
    const short* Bptr[NBC]; short* Blds[NBC];
    #pragma unroll
    for (int t = 0; t < NBC; ++t) {
        const int c = t * 256 + tid;
        const int row = c >> 3, sl = c & 7;
        Bptr[t] = Bb + (size_t)(n0 + row) * ldb + ((sl ^ (row & 7)) * 8);
        Blds[t] = Bs + c * 8;
    }

    const int nsteps = (kend - k0) >> 6;

    // prologue: stage buffer 0
    #pragma unroll
    for (int t = 0; t < NA; ++t)  gload_lds16(Aptr[t] + k0, Alds[t]);
    #pragma unroll
    for (int t = 0; t < NBC; ++t) gload_lds16(Bptr[t] + k0, Blds[t]);
    __syncthreads();

    for (int it = 0; it < nsteps; ++it) {
        const short* Ac = As + (it & 1) * ASZ;
        const short* Bc = Bs + (it & 1) * BSZ;

        // (1) read all fragments of cur into registers (static indices -> VGPRs)
        short8 fa[4][FM], fb[4][FN];
        #pragma unroll
        for (int t4 = 0; t4 < 4; ++t4) {
            const int g = 2 * t4 + h;             // k-octet index 0..7
            #pragma unroll
            for (int i = 0; i < FM; ++i) {
                const int row = wr * 32 * FM + i * 32 + u31;
                fa[t4][i] = *(const short8*)(Ac + row * 64 + ((g ^ (row & 7)) * 8));
            }
            #pragma unroll
            for (int j = 0; j < FN; ++j) {
                const int row = wc * 32 * FN + j * 32 + u31;
                fb[t4][j] = *(const short8*)(Bc + row * 64 + ((g ^ (row & 7)) * 8));
            }
        }

        // (2) issue next-tile staging into the other buffer (in flight during MFMA)
        if (it + 1 < nsteps) {
            const int c1 = k0 + (it + 1) * 64;
            const int nb = (it & 1) ^ 1;
            #pragma unroll
            for (int t = 0; t < NA; ++t)  gload_lds16(Aptr[t] + c1, Alds[t] + nb * ASZ);
            #pragma unroll
            for (int t = 0; t < NBC; ++t) gload_lds16(Bptr[t] + c1, Blds[t] + nb * BSZ);
        }

        // (3) MFMA
        #pragma unroll
        for (int t4 = 0; t4 < 4; ++t4)
            #pragma unroll
            for (int i = 0; i < FM; ++i)
                #pragma unroll
                for (int j = 0; j < FN; ++j)
                    acc[i][j] = __builtin_amdgcn_mfma_f32_32x32x16_bf16(fa[t4][i], fb[t4][j], acc[i][j], 0, 0, 0);

        // (4) one barrier per step: drains this step's gloads (issued ~400+ cy ago)
        __syncthreads();
    }
}

// ---------------- both conv weight casts in one dispatch ----------------
__global__ __launch_bounds__(256) void wcast2_k(const float* __restrict__ wq,
                                                const float* __restrict__ wk,
                                                short* __restrict__ Wb) {
    const float* W = blockIdx.y ? wk : wq;
    short* D = Wb + (size_t)blockIdx.y * CCH * CCH;
    int i = (blockIdx.x * 256 + threadIdx.x) * 4;
    float4 v = *(const float4*)(W + i);
    u16x4 u;
    u.x = f2bf(v.x); u.y = f2bf(v.y); u.z = f2bf(v.z); u.w = f2bf(v.w);
    *(u16x4*)(D + i) = u;
}

__global__ __launch_bounds__(256) void wcast_k(const float* __restrict__ W,
                                               short* __restrict__ Wb) {
    int i = (blockIdx.x * 256 + threadIdx.x) * 4;
    float4 v = *(const float4*)(W + i);
    u16x4 u;
    u.x = f2bf(v.x); u.y = f2bf(v.y); u.z = f2bf(v.z); u.w = f2bf(v.w);
    *(u16x4*)(Wb + i) = u;
}

// ---------------- merged transpose-cast: tgt & ref [b][c][l] fp32 -> T1[which][b][l][c] bf16 ----
__global__ __launch_bounds__(256) void tcast_k(const float* __restrict__ tgt,
                                               const float* __restrict__ ref,
                                               short* __restrict__ T1) {
    __shared__ float tile[32][33];
    const int z = blockIdx.z;
    const int b = z & 3, which = z >> 2;
    const float* X = (which ? ref : tgt) + (size_t)b * CCH * LPIX;
    const int c0 = blockIdx.y * 32;
    const int l0 = blockIdx.x * 32;
    const int tx = threadIdx.x, ty = threadIdx.y;
    #pragma unroll
    for (int j = 0; j < 4; ++j)
        tile[ty + j * 8][tx] = X[(size_t)(c0 + ty + j * 8) * LPIX + l0 + tx];
    __syncthreads();
    short* D = T1 + ((size_t)(which * NB + b) * LPIX) * CCH;
    #pragma unroll
    for (int j = 0; j < 4; ++j)
        D[(size_t)(l0 + ty + j * 8) * CCH + c0 + tx] = (short)f2bf(tile[tx][ty + j * 8]);
}

// ---------------- merged q/k conv: C[2304 bl x 2048 o] = T1[which] x W[which]^T ----------
// 576 blocks of 128x128, XCD-swizzled: xcd owns 4 o-slabs (2 MB weights, L2-resident),
// each reused by 18 bl-tiles. Fused bias + channel-sqnorm atomics.
__global__ __launch_bounds__(256) void conv_k(
    const short* __restrict__ T1, const short* __restrict__ Wb,
    const float* __restrict__ bq, const float* __restrict__ bk,
    short* __restrict__ x2t, short* __restrict__ kt,
    float* __restrict__ nq, float* __restrict__ nk)
{
    __shared__ short As[2 * 128 * 64];   // 32 KB (dbuf)
    __shared__ short Bs[2 * 128 * 64];   // 32 KB (dbuf)
    const int id = blockIdx.x;
    const int xcd = id & 7, slot = id >> 3;          // slot 0..71
    const int sid = xcd * 4 + slot / 18;             // o-slab 0..31
    const int which = sid >> 4;
    const int n0 = (sid & 15) * 128;                 // o
    const int m0 = (slot % 18) * 128;                // bl
    const short* Ab = T1 + (size_t)which * (NB * LPIX) * CCH;
    const short* Bb = Wb + (size_t)which * CCH * CCH;
    const float* bias = which ? bk : bq;
    short* Yb = which ? kt : x2t;
    const int ldy = which ? CCH : 4096;
    float* Narr = which ? nk : nq;

    f32x16 acc[2][2] = {};
    mm32_core<128, 128, 2, 2>(Ab, CCH, Bb, CCH, 0, CCH, As, Bs, m0, n0, acc);

    const int lane = threadIdx.x & 63, w = threadIdx.x >> 6;
    const int wr = w & 1, wc = w >> 1;
    const int u31 = lane & 31, h = lane >> 5;
    #pragma unroll
    for (int i = 0; i < 2; ++i) {
        float pv[16];
        #pragma unroll
        for (int r = 0; r < 16; ++r) pv[r] = 0.f;
        #pragma unroll
        for (int j = 0; j < 2; ++j) {
            const int gn = n0 + wc * 64 + j * 32 + u31;
            const float bi = bias[gn];
            #pragma unroll
            for (int r = 0; r < 16; ++r) {
                const int gm = m0 + wr * 64 + i * 32 + ROW32(r, h);
                float v = acc[i][j][r] + bi;
                pv[r] += v * v;
                Yb[(size_t)gm * ldy + gn] = (short)f2bf(v);
            }
        }
        #pragma unroll
        for (int r = 0; r < 16; ++r) {
            float s = pv[r];
            #pragma unroll
            for (int m = 1; m < 32; m <<= 1) s += __shfl_xor(s, m);
            if (u31 == 0) {
                const int gm = m0 + wr * 64 + i * 32 + ROW32(r, h);
                atomicAdd(&Narr[gm], s);
            }
        }
    }
}

// ---------------- gram with split-K2: M_part[kc][b][lr][lt], 64x64 tiles ----------------
__global__ __launch_bounds__(256) void gram_k(
    const short* __restrict__ kt, const short* __restrict__ x2t,
    float* __restrict__ Mpart)
{
    __shared__ short As[2 * 64 * 64];    // 16 KB (dbuf)
    __shared__ short Bs[2 * 64 * 64];    // 16 KB (dbuf)
    const int z = blockIdx.z;
    const int b = z >> 1, kc = z & 1;
    const short* Ab = kt + (size_t)b * LPIX * CCH;
    const short* Bb = x2t + (size_t)b * LPIX * 4096;
    const int m0 = blockIdx.y * 64;   // lr
    const int n0 = blockIdx.x * 64;   // lt
    f32x16 acc[1][1] = {};
    mm32_core<64, 64, 1, 1>(Ab, CCH, Bb, 4096, kc * 1024, kc * 1024 + 1024, As, Bs, m0, n0, acc);
    float* Mb = Mpart + (size_t)(kc * NB + b) * LPIX * LPIX;
    const int lane = threadIdx.x & 63, w = threadIdx.x >> 6;
    const int wr = w & 1, wc = w >> 1;
    const int u31 = lane & 31, h = lane >> 5;
    const int gn = n0 + wc * 32 + u31;
    #pragma unroll
    for (int r = 0; r < 16; ++r) {
        const int gm = m0 + wr * 32 + ROW32(r, h);
        Mb[(size_t)gm * LPIX + gn] = acc[0][0][r];
    }
}

// ---------------- final: out[o][bl] = W[2048x4096] x x2t[2304x4096]^T, split-K2 ----------
// 576 blocks of 128(o) x 128(bl) x 2048(k-half). The two k-halves accumulate into `out`
// via atomicAdd (exact: per address the two adds commute bitwise); out is zeroed at
// stream start. Epilogue terms folded so that sum = (acc0+acc1+bt)*S + PT.
// XCD-swizzled: xcd owns 4 (o-tile, kc) A-slabs (2 MB, L2-resident) x 18 bl-tiles.
__global__ __launch_bounds__(256) void fin_k(
    const short* __restrict__ wtb, const short* __restrict__ x2t,
    const float* __restrict__ bt, const float* __restrict__ S,
    const float* __restrict__ PT, float* __restrict__ out)
{
    __shared__ short As[2 * 128 * 64];   // 32 KB (dbuf)
    __shared__ short Bs[2 * 128 * 64];   // 32 KB (dbuf)
    const int id = blockIdx.x;
    const int xcd = id & 7, slot = id >> 3;          // slot 0..71
    const int sid = xcd * 4 + slot / 18;             // 0..31
    const int kc = sid >> 4;
    const int m0 = (sid & 15) * 128;                 // o
    const int n0 = (slot % 18) * 128;                // bl
    f32x16 acc[2][2] = {};
    mm32_core<128, 128, 2, 2>(wtb, 4096, x2t, 4096, kc * 2048, kc * 2048 + 2048,
                              As, Bs, m0, n0, acc);
    const int lane = threadIdx.x & 63, w = threadIdx.x >> 6;
    const int wr = w & 1, wc = w >> 1;
    const int u31 = lane & 31, h = lane >> 5;
    #pragma unroll
    for (int i = 0; i < 2; ++i)
        #pragma unroll
        for (int j = 0; j < 2; ++j) {
            const int gn = n0 + wc * 64 + j * 32 + u31;   // bl (576%32==0: b uniform/32 lanes)
            const int bb = gn / LPIX;
            const int l  = gn - bb * LPIX;
            const float sv = S[gn];
            #pragma unroll
            for (int r = 0; r < 16; ++r) {
                const int gm = m0 + wr * 64 + i * 32 + ROW32(r, h);
                const size_t idx = ((size_t)bb * CCH + gm) * LPIX + l;
                float v = kc ? (acc[i][j][r] + bt[gm]) * sv + PT[idx]
                             : acc[i][j][r] * sv;
                atomicAdd(&out[idx], v);
            }
        }
}

// ---------------- stage 1: fused 3x3-box invNk + 9-tap aggregation + chunk argmax ----
__global__ __launch_bounds__(256) void argmax1_k(
    const float* __restrict__ Mpart, const float* __restrict__ nk,
    float* __restrict__ Pv, int* __restrict__ Pi)
{
    const int b   = blockIdx.z;
    const int lrb = blockIdx.y;                 // ir row 0..23
    const int tx = threadIdx.x, ty = threadIdx.y;
    const int tid = ty * 64 + tx;
    __shared__ float invNkS[24];
    if (tid < 24) {
        const int jr = tid;
        float s = 0.f;
        #pragma unroll
        for (int di = -1; di <= 1; ++di) {
            const int ii = lrb + di;
            if ((unsigned)ii > 23u) continue;
            #pragma unroll
            for (int dj = -1; dj <= 1; ++dj) {
                const int jj = jr + dj;
                if ((unsigned)jj > 23u) continue;
                s += nk[b * LPIX + ii * 24 + jj];
            }
        }
        invNkS[jr] = 1.0f / fmaxf(sqrtf(s), 1e-12f);
    }
    __syncthreads();
    const int lt = blockIdx.x * 64 + tx;
    const int it = lt / 24, jt = lt % 24;
    const float* Mb0 = Mpart + (size_t)b * LPIX * LPIX;
    const float* Mb1 = Mpart + (size_t)(NB + b) * LPIX * LPIX;
    float best = -1e30f; int bidx = 0;
    #pragma unroll
    for (int i = 0; i < 6; ++i) {
        const int jr = ty + i * 4;
        const int lr = lrb * 24 + jr;
        const int base = lr * LPIX + lt;
        float g = 0.f;
        #pragma unroll
        for (int di = -1; di <= 1; ++di) {
            if ((unsigned)(lrb + di) > 23u || (unsigned)(it + di) > 23u) continue;
            #pragma unroll
            for (int dj = -1; dj <= 1; ++dj) {
                if ((unsigned)(jr + dj) > 23u || (unsigned)(jt + dj) > 23u) continue;
                const int o = base + (di * 24 + dj) * (LPIX + 1);
                g += Mb0[o] + Mb1[o];
            }
        }
        float v = g * invNkS[jr];
        if (v > best) { best = v; bidx = lr; }
    }
    __shared__ float rv[4][64];
    __shared__ int   ri[4][64];
    rv[ty][tx] = best; ri[ty][tx] = bidx;
    __syncthreads();
    if (ty == 0) {
        #pragma unroll
        for (int y = 1; y < 4; ++y) {
            float v = rv[y][tx]; int id = ri[y][tx];
            if (v > best || (v == best && id < bidx)) { best = v; bidx = id; }
        }
        Pv[((size_t)b * 24 + lrb) * LPIX + lt] = best;
        Pi[((size_t)b * 24 + lrb) * LPIX + lt] = bidx;
    }
}

// ---------------- stage 2: fold 24 partials, fused invNq ----------------
__global__ __launch_bounds__(256) void argmax2_k(
    const float* __restrict__ Pv, const int* __restrict__ Pi,
    const float* __restrict__ nq,
    float* __restrict__ S, int* __restrict__ Arg)
{
    int idx = blockIdx.x * 256 + threadIdx.x;
    if (idx >= NB * LPIX) return;
    int b = idx / LPIX, lt = idx % LPIX;
    int it = lt / 24, jt = lt % 24;
    float s = 0.f;
    #pragma unroll
    for (int di = -1; di <= 1; ++di) {
        const int ii = it + di;
        if ((unsigned)ii > 23u) continue;
        #pragma unroll
        for (int dj = -1; dj <= 1; ++dj) {
            const int jj = jt + dj;
            if ((unsigned)jj > 23u) continue;
            s += nq[b * LPIX + ii * 24 + jj];
        }
    }
    const float invNq = 1.0f / fmaxf(sqrtf(s), 1e-12f);
    float best = -1e30f; int bidx = 0;
    #pragma unroll
    for (int c = 0; c < 24; ++c) {
        float v = Pv[((size_t)b * 24 + c) * LPIX + lt];
        int  id = Pi[((size_t)b * 24 + c) * LPIX + lt];
        if (v > best || (v == best && id < bidx)) { best = v; bidx = id; }
    }
    S[idx]   = best * invNq;
    Arg[idx] = bidx;
}

// ---------------- gather best ref patches + fold (/9), XCD-swizzled ----------------
// 1D grid 576: XCD pair owns one b (kt[b]=2.36 MB L2-resident)
__global__ __launch_bounds__(256) void gather_k(
    const short* __restrict__ kt, const int* __restrict__ Arg,
    short* __restrict__ x2t)
{
    const int id = blockIdx.x;
    const int xcd = id & 7, slot = id >> 3;          // slot 0..71
    const int b  = xcd >> 1;
    const int l0 = ((xcd & 1) * 72 + slot) * 4;
    const int lane = threadIdx.x, ty = threadIdx.y;
    const int tid = ty * 64 + lane;
    __shared__ int tap[4][9];
    if (tid < 36) {
        int px = tid / 9, t9 = tid % 9;
        int l = l0 + px;
        int i = l / 24, j = l % 24;
        int ki = t9 / 3, kj = t9 % 3;
        int ip = i + 1 - ki, jp = j + 1 - kj;
        int off = -1;
        if (ip >= 0 && ip < 24 && jp >= 0 && jp < 24) {
            int a = Arg[b * LPIX + ip * 24 + jp];
            int rr = a / 24 + ki - 1;
            int cc = a % 24 + kj - 1;
            if (rr >= 0 && rr < 24 && cc >= 0 && cc < 24) off = rr * 24 + cc;
        }
        tap[px][t9] = off;
    }
    __syncthreads();
    const int l = l0 + ty;
    const short* Kb = kt + (size_t)b * LPIX * CCH;
    short* dst = x2t + ((size_t)b * LPIX + l) * 4096 + CCH;
    int t[9];
    #pragma unroll
    for (int i = 0; i < 9; ++i) t[i] = tap[ty][i];
    const float inv9 = 1.0f / 9.0f;
    #pragma unroll
    for (int j = 0; j < 8; ++j) {
        int c = (lane + j * 64) * 4;
        float s0 = 0.f, s1 = 0.f, s2 = 0.f, s3 = 0.f;
        #pragma unroll
        for (int t9 = 0; t9 < 9; ++t9) {
            int off = t[t9];
            if (off < 0) continue;
            u16x4 u = *(const u16x4*)(Kb + (size_t)off * CCH + c);
            s0 += bf2f(u.x); s1 += bf2f(u.y); s2 += bf2f(u.z); s3 += bf2f(u.w);
        }
        u16x4 o;
        o.x = f2bf(s0 * inv9); o.y = f2bf(s1 * inv9);
        o.z = f2bf(s2 * inv9); o.w = f2bf(s3 * inv9);
        *(u16x4*)(dst + c) = o;
    }
}

extern "C" void kernel_launch(void* const* d_in, const int* in_sizes, int n_in,
                              void* d_out, int out_size, void* d_ws, size_t ws_size,
                              hipStream_t stream) {
    const float* part_ref = (const float*)d_in[0];
    const float* part_tgt = (const float*)d_in[1];
    const float* wq = (const float*)d_in[2];
    const float* bq = (const float*)d_in[3];
    const float* wk = (const float*)d_in[4];
    const float* bk = (const float*)d_in[5];
    const float* wt = (const float*)d_in[6];
    const float* bt = (const float*)d_in[7];
    float* out = (float*)d_out;

    short* wqb2 = (short*)d_ws;
    short* wtb  = wqb2;                                       // reuse after convs
    short* T1   = wqb2 + (size_t)2 * CCH * CCH;
    short* kt   = T1 + (size_t)2 * NB * LPIX * CCH;
    short* x2t  = kt + (size_t)NB * LPIX * CCH;
    float* Mpart = (float*)T1;                                // aliases T1 (dead by gram time)
    float* nk    = (float*)(x2t + (size_t)NB * LPIX * 4096);
    float* nq    = nk + NB * LPIX;
    float* Sbuf  = nq + NB * LPIX;
    int*   Arg   = (int*)(Sbuf + NB * LPIX);
    float* Pv    = (float*)(Arg + NB * LPIX);                 // 24*NB*LPIX
    int*   Pi    = (int*)(Pv + (size_t)24 * NB * LPIX);

    hipMemsetAsync(nk, 0, 2 * NB * LPIX * sizeof(float), stream);  // nk|nq contiguous
    hipMemsetAsync(out, 0, (size_t)NB * CCH * LPIX * sizeof(float), stream);  // fin accumulates

    wcast2_k<<<dim3(4096, 2), 256, 0, stream>>>(wq, wk, wqb2);
    tcast_k<<<dim3(18, 64, 8), dim3(32, 8), 0, stream>>>(part_tgt, part_ref, T1);

    // q -> x2t[:, :, 0:2048]; k -> kt; fused channel-norm atomics (576 blocks, swizzled)
    conv_k<<<576, 256, 0, stream>>>(T1, wqb2, bq, bk, x2t, kt, nq, nk);

    // gram split-K2 -> Mpart (648 blocks)
    gram_k<<<dim3(9, 9, 8), 256, 0, stream>>>(kt, x2t, Mpart);

    argmax1_k<<<dim3(9, 24, NB), dim3(64, 4), 0, stream>>>(Mpart, nk, Pv, Pi);
    argmax2_k<<<9, 256, 0, stream>>>(Pv, Pi, nq, Sbuf, Arg);

    gather_k<<<576, dim3(64, 4), 0, stream>>>(kt, Arg, x2t);

    wcast_k<<<8192, 256, 0, stream>>>(wt, wtb);
    // final fused conv, split-K2 atomic accumulate (576 blocks, swizzled)
    fin_k<<<576, 256, 0, stream>>>(wtb, x2t, bt, Sbuf, part_tgt, out);
}

// Round 4
// 377.293 us; speedup vs baseline: 1.1338x; 1.1338x over previous
//
#include <hip/hip_runtime.h>
#include <cstddef>
#include <cstdint>

#define LPIX 576
#define CCH  2048
#define NB   4

typedef __attribute__((ext_vector_type(8))) short short8;
typedef __attribute__((ext_vector_type(4))) float f32x4;
typedef __attribute__((ext_vector_type(4))) unsigned short u16x4;

__device__ __forceinline__ unsigned short f2bf(float f) {
    uint32_t u = __builtin_bit_cast(uint32_t, f);
    u += 0x7fff + ((u >> 16) & 1);          // round-to-nearest-even
    return (unsigned short)(u >> 16);
}
__device__ __forceinline__ float bf2f(unsigned short s) {
    return __builtin_bit_cast(float, (uint32_t)s << 16);
}

__device__ __forceinline__ void gload_lds16(const void* g, void* l) {
    __builtin_amdgcn_global_load_lds((const __attribute__((address_space(1))) void*)g,
                                     (__attribute__((address_space(3))) void*)l, 16, 0, 0);
}

// ---------------- MFMA K-loop, BK=64 twin 32-k panels (round-0 proven core) ----------------
// Per-wave output tile = (BM/2)x(BN/2). At <128,128>: 64x64/wave = m97's verified geometry
// (per 32-k panel: 8 ds_read_b128 + 16 MFMA per thread -> 0.5 reads/MFMA).
template<int BM, int BN>
__device__ __forceinline__ void mm_core64(
    const short* __restrict__ Ab, int lda,
    const short* __restrict__ Bb, int ldb,
    int k0, int kend, short* As, short* Bs,
    int m0, int n0, f32x4 (&acc)[BM/32][BN/32])
{
    const int tid  = threadIdx.x;
    const int lane = tid & 63;
    const int w    = tid >> 6;
    const int wm = (w & 1) * (BM / 2);
    const int wn = (w >> 1) * (BN / 2);
    const int l15 = lane & 15;
    const int k8  = (lane >> 4) * 8;
    const int r   = tid >> 2;          // 0..63
    const int kk  = (tid & 3) * 8;     // 0,8,16,24 within a 32-k panel

    const short* Aptr[BM / 32]; short* Alds[BM / 32];
    #pragma unroll
    for (int u = 0; u < BM / 32; ++u) {
        const int p = u & 1, g = u >> 1;
        Aptr[u] = Ab + (size_t)(m0 + g * 64 + r) * lda + p * 32 + kk;
        Alds[u] = As + p * BM * 32 + g * 2048 + tid * 8;
    }
    const short* Bptr[BN / 32]; short* Blds[BN / 32];
    #pragma unroll
    for (int u = 0; u < BN / 32; ++u) {
        const int p = u & 1, g = u >> 1;
        Bptr[u] = Bb + (size_t)(n0 + g * 64 + r) * ldb + p * 32 + kk;
        Blds[u] = Bs + p * BN * 32 + g * 2048 + tid * 8;
    }

    for (int c0 = k0; c0 < kend; c0 += 64) {
        #pragma unroll
        for (int u = 0; u < BM / 32; ++u) gload_lds16(Aptr[u] + c0, Alds[u]);
        #pragma unroll
        for (int u = 0; u < BN / 32; ++u) gload_lds16(Bptr[u] + c0, Blds[u]);
        __syncthreads();
        #pragma unroll
        for (int s = 0; s < 2; ++s) {
            short8 fa[BM / 32], fb[BN / 32];
            #pragma unroll
            for (int i = 0; i < BM / 32; ++i)
                fa[i] = *(const short8*)(As + s * BM * 32 + (wm + i * 16 + l15) * 32 + k8);
            #pragma unroll
            for (int j = 0; j < BN / 32; ++j)
                fb[j] = *(const short8*)(Bs + s * BN * 32 + (wn + j * 16 + l15) * 32 + k8);
            #pragma unroll
            for (int i = 0; i < BM / 32; ++i)
                #pragma unroll
                for (int j = 0; j < BN / 32; ++j)
                    acc[i][j] = __builtin_amdgcn_mfma_f32_16x16x32_bf16(fa[i], fb[j], acc[i][j], 0, 0, 0);
        }
        __syncthreads();
    }
}

// ---------------- both conv weight casts in one dispatch ----------------
__global__ __launch_bounds__(256) void wcast2_k(const float* __restrict__ wq,
                                                const float* __restrict__ wk,
                                                short* __restrict__ Wb) {
    const float* W = blockIdx.y ? wk : wq;
    short* D = Wb + (size_t)blockIdx.y * CCH * CCH;
    int i = (blockIdx.x * 256 + threadIdx.x) * 4;
    float4 v = *(const float4*)(W + i);
    u16x4 u;
    u.x = f2bf(v.x); u.y = f2bf(v.y); u.z = f2bf(v.z); u.w = f2bf(v.w);
    *(u16x4*)(D + i) = u;
}

__global__ __launch_bounds__(256) void wcast_k(const float* __restrict__ W,
                                               short* __restrict__ Wb) {
    int i = (blockIdx.x * 256 + threadIdx.x) * 4;
    float4 v = *(const float4*)(W + i);
    u16x4 u;
    u.x = f2bf(v.x); u.y = f2bf(v.y); u.z = f2bf(v.z); u.w = f2bf(v.w);
    *(u16x4*)(Wb + i) = u;
}

// ---------------- merged transpose-cast: tgt & ref [b][c][l] fp32 -> T1[which][b][l][c] bf16 ----
__global__ __launch_bounds__(256) void tcast_k(const float* __restrict__ tgt,
                                               const float* __restrict__ ref,
                                               short* __restrict__ T1) {
    __shared__ float tile[32][33];
    const int z = blockIdx.z;
    const int b = z & 3, which = z >> 2;
    const float* X = (which ? ref : tgt) + (size_t)b * CCH * LPIX;
    const int c0 = blockIdx.y * 32;
    const int l0 = blockIdx.x * 32;
    const int tx = threadIdx.x, ty = threadIdx.y;
    #pragma unroll
    for (int j = 0; j < 4; ++j)
        tile[ty + j * 8][tx] = X[(size_t)(c0 + ty + j * 8) * LPIX + l0 + tx];
    __syncthreads();
    short* D = T1 + ((size_t)(which * NB + b) * LPIX) * CCH;
    #pragma unroll
    for (int j = 0; j < 4; ++j)
        D[(size_t)(l0 + ty + j * 8) * CCH + c0 + tx] = (short)f2bf(tile[tx][ty + j * 8]);
}

// ---------------- merged q/k conv: 128(bl) x 128(o) tiles, m97 geometry ----------
// 576 blocks, XCD-swizzled: xcd owns 4 o-slabs (2 MB weights, L2-resident),
// each reused by 18 bl-tiles. Fused bias + channel-sqnorm atomics.
__global__ __launch_bounds__(256) void conv_k(
    const short* __restrict__ T1, const short* __restrict__ Wb,
    const float* __restrict__ bq, const float* __restrict__ bk,
    short* __restrict__ x2t, short* __restrict__ kt,
    float* __restrict__ nq, float* __restrict__ nk)
{
    __shared__ short As[128 * 64];   // 16 KB
    __shared__ short Bs[128 * 64];   // 16 KB
    const int id = blockIdx.x;
    const int xcd = id & 7, slot = id >> 3;          // slot 0..71
    const int sid = xcd * 4 + slot / 18;             // o-slab 0..31
    const int which = sid >> 4;
    const int n0 = (sid & 15) * 128;                 // o
    const int m0 = (slot % 18) * 128;                // bl (contiguous over b: T1[which] is [2304][2048])
    const short* Ab = T1 + (size_t)which * (NB * LPIX) * CCH;
    const short* Bb = Wb + (size_t)which * CCH * CCH;
    const float* bias = which ? bk : bq;
    short* Yb = which ? kt : x2t;
    const int ldy = which ? CCH : 4096;
    float* Narr = which ? nk : nq;                   // [NB*LPIX], indexed by gm = b*576+l

    f32x4 acc[4][4] = {};
    mm_core64<128, 128>(Ab, CCH, Bb, CCH, 0, CCH, As, Bs, m0, n0, acc);

    const int lane = threadIdx.x & 63, w = threadIdx.x >> 6;
    const int wm = (w & 1) * 64, wn = (w >> 1) * 64;
    const int l15 = lane & 15, quad = lane >> 4;
    float pv[4][4] = {};
    #pragma unroll
    for (int i = 0; i < 4; ++i)
        #pragma unroll
        for (int j = 0; j < 4; ++j) {
            const int gn = n0 + wn + j * 16 + l15;
            const float bi = bias[gn];
            #pragma unroll
            for (int r = 0; r < 4; ++r) {
                const int gm = m0 + wm + i * 16 + quad * 4 + r;
                float v = acc[i][j][r] + bi;
                pv[i][r] += v * v;
                Yb[(size_t)gm * ldy + gn] = (short)f2bf(v);
            }
        }
    // reduce pv over the 16 lanes sharing (i,quad,r), then atomic into norm buffer
    #pragma unroll
    for (int i = 0; i < 4; ++i)
        #pragma unroll
        for (int r = 0; r < 4; ++r) {
            float s = pv[i][r];
            #pragma unroll
            for (int m = 1; m < 16; m <<= 1) s += __shfl_xor(s, m);
            if (l15 == 0) {
                const int gm = m0 + wm + i * 16 + quad * 4 + r;
                atomicAdd(&Narr[gm], s);
            }
        }
}

// ---------------- gram with split-K2: M_part[kc][b][lr][lt], 64x64 tiles ----------------
__global__ __launch_bounds__(256) void gram_k(
    const short* __restrict__ kt, const short* __restrict__ x2t,
    float* __restrict__ Mpart)
{
    __shared__ short As[64 * 64];
    __shared__ short Bs[64 * 64];
    const int z = blockIdx.z;
    const int b = z >> 1, kc = z & 1;
    const short* Ab = kt + (size_t)b * LPIX * CCH;
    const short* Bb = x2t + (size_t)b * LPIX * 4096;
    const int m0 = blockIdx.y * 64;   // lr
    const int n0 = blockIdx.x * 64;   // lt
    f32x4 acc[2][2] = {};
    mm_core64<64, 64>(Ab, CCH, Bb, 4096, kc * 1024, kc * 1024 + 1024, As, Bs, m0, n0, acc);
    float* Mb = Mpart + (size_t)(kc * NB + b) * LPIX * LPIX;
    const int lane = threadIdx.x & 63, w = threadIdx.x >> 6;
    const int wm = (w & 1) * 32, wn = (w >> 1) * 32;
    const int l15 = lane & 15, quad = lane >> 4;
    #pragma unroll
    for (int i = 0; i < 2; ++i)
        #pragma unroll
        for (int j = 0; j < 2; ++j) {
            const int gn = n0 + wn + j * 16 + l15;
            #pragma unroll
            for (int r = 0; r < 4; ++r) {
                const int gm = m0 + wm + i * 16 + quad * 4 + r;
                Mb[(size_t)gm * LPIX + gn] = acc[i][j][r];
            }
        }
}

// ---------------- final: 128(o) x 128(bl) tiles, m97 geometry, epilogue bias + *S + PT ----
// 288 blocks (16 o-tiles x 18 bl-tiles), XCD-swizzled: xcd owns 2 o-tiles
// (2 MB weights, L2-resident) x 18 bl-tiles. No split-K, direct store.
__global__ __launch_bounds__(256) void fin_k(
    const short* __restrict__ wtb, const short* __restrict__ x2t,
    const float* __restrict__ bt, const float* __restrict__ S,
    const float* __restrict__ PT, float* __restrict__ out)
{
    __shared__ short As[128 * 64];   // 16 KB
    __shared__ short Bs[128 * 64];   // 16 KB
    const int id = blockIdx.x;
    const int xcd = id & 7, slot = id >> 3;          // slot 0..35
    const int sid = xcd * 2 + slot / 18;             // o-tile 0..15
    const int m0 = sid * 128;                        // o
    const int n0 = (slot % 18) * 128;                // bl
    f32x4 acc[4][4] = {};
    mm_core64<128, 128>(wtb, 4096, x2t, 4096, 0, 4096, As, Bs, m0, n0, acc);
    const int lane = threadIdx.x & 63, w = threadIdx.x >> 6;
    const int wm = (w & 1) * 64, wn = (w >> 1) * 64;
    const int l15 = lane & 15, quad = lane >> 4;
    #pragma unroll
    for (int i = 0; i < 4; ++i)
        #pragma unroll
        for (int j = 0; j < 4; ++j) {
            const int gn = n0 + wn + j * 16 + l15;   // bl = b*576 + l
            const int bb = gn / LPIX;
            const int l  = gn - bb * LPIX;
            const float sv = S[gn];
            #pragma unroll
            for (int r = 0; r < 4; ++r) {
                const int gm = m0 + wm + i * 16 + quad * 4 + r;
                const size_t idx = ((size_t)bb * CCH + gm) * LPIX + l;
                out[idx] = (acc[i][j][r] + bt[gm]) * sv + PT[idx];
            }
        }
}

// ---------------- stage 1: fused 3x3-box invNk + 9-tap aggregation + chunk argmax ----
__global__ __launch_bounds__(256) void argmax1_k(
    const float* __restrict__ Mpart, const float* __restrict__ nk,
    float* __restrict__ Pv, int* __restrict__ Pi)
{
    const int b   = blockIdx.z;
    const int lrb = blockIdx.y;                 // ir row 0..23
    const int tx = threadIdx.x, ty = threadIdx.y;
    const int tid = ty * 64 + tx;
    __shared__ float invNkS[24];
    if (tid < 24) {
        const int jr = tid;
        float s = 0.f;
        #pragma unroll
        for (int di = -1; di <= 1; ++di) {
            const int ii = lrb + di;
            if ((unsigned)ii > 23u) continue;
            #pragma unroll
            for (int dj = -1; dj <= 1; ++dj) {
                const int jj = jr + dj;
                if ((unsigned)jj > 23u) continue;
                s += nk[b * LPIX + ii * 24 + jj];
            }
        }
        invNkS[jr] = 1.0f / fmaxf(sqrtf(s), 1e-12f);
    }
    __syncthreads();
    const int lt = blockIdx.x * 64 + tx;
    const int it = lt / 24, jt = lt % 24;
    const float* Mb0 = Mpart + (size_t)b * LPIX * LPIX;
    const float* Mb1 = Mpart + (size_t)(NB + b) * LPIX * LPIX;
    float best = -1e30f; int bidx = 0;
    #pragma unroll
    for (int i = 0; i < 6; ++i) {
        const int jr = ty + i * 4;
        const int lr = lrb * 24 + jr;
        const int base = lr * LPIX + lt;
        float g = 0.f;
        #pragma unroll
        for (int di = -1; di <= 1; ++di) {
            if ((unsigned)(lrb + di) > 23u || (unsigned)(it + di) > 23u) continue;
            #pragma unroll
            for (int dj = -1; dj <= 1; ++dj) {
                if ((unsigned)(jr + dj) > 23u || (unsigned)(jt + dj) > 23u) continue;
                const int o = base + (di * 24 + dj) * (LPIX + 1);
                g += Mb0[o] + Mb1[o];
            }
        }
        float v = g * invNkS[jr];
        if (v > best) { best = v; bidx = lr; }
    }
    __shared__ float rv[4][64];
    __shared__ int   ri[4][64];
    rv[ty][tx] = best; ri[ty][tx] = bidx;
    __syncthreads();
    if (ty == 0) {
        #pragma unroll
        for (int y = 1; y < 4; ++y) {
            float v = rv[y][tx]; int id = ri[y][tx];
            if (v > best || (v == best && id < bidx)) { best = v; bidx = id; }
        }
        Pv[((size_t)b * 24 + lrb) * LPIX + lt] = best;
        Pi[((size_t)b * 24 + lrb) * LPIX + lt] = bidx;
    }
}

// ---------------- stage 2: fold 24 partials, fused invNq ----------------
__global__ __launch_bounds__(256) void argmax2_k(
    const float* __restrict__ Pv, const int* __restrict__ Pi,
    const float* __restrict__ nq,
    float* __restrict__ S, int* __restrict__ Arg)
{
    int idx = blockIdx.x * 256 + threadIdx.x;
    if (idx >= NB * LPIX) return;
    int b = idx / LPIX, lt = idx % LPIX;
    int it = lt / 24, jt = lt % 24;
    float s = 0.f;
    #pragma unroll
    for (int di = -1; di <= 1; ++di) {
        const int ii = it + di;
        if ((unsigned)ii > 23u) continue;
        #pragma unroll
        for (int dj = -1; dj <= 1; ++dj) {
            const int jj = jt + dj;
            if ((unsigned)jj > 23u) continue;
            s += nq[b * LPIX + ii * 24 + jj];
        }
    }
    const float invNq = 1.0f / fmaxf(sqrtf(s), 1e-12f);
    float best = -1e30f; int bidx = 0;
    #pragma unroll
    for (int c = 0; c < 24; ++c) {
        float v = Pv[((size_t)b * 24 + c) * LPIX + lt];
        int  id = Pi[((size_t)b * 24 + c) * LPIX + lt];
        if (v > best || (v == best && id < bidx)) { best = v; bidx = id; }
    }
    S[idx]   = best * invNq;
    Arg[idx] = bidx;
}

// ---------------- gather best ref patches + fold (/9), XCD-swizzled ----------------
// 1D grid 576: XCD pair owns one b (kt[b]=2.36 MB L2-resident)
__global__ __launch_bounds__(256) void gather_k(
    const short* __restrict__ kt, const int* __restrict__ Arg,
    short* __restrict__ x2t)
{
    const int id = blockIdx.x;
    const int xcd = id & 7, slot = id >> 3;          // slot 0..71
    const int b  = xcd >> 1;
    const int l0 = ((xcd & 1) * 72 + slot) * 4;
    const int lane = threadIdx.x, ty = threadIdx.y;
    const int tid = ty * 64 + lane;
    __shared__ int tap[4][9];
    if (tid < 36) {
        int px = tid / 9, t9 = tid % 9;
        int l = l0 + px;
        int i = l / 24, j = l % 24;
        int ki = t9 / 3, kj = t9 % 3;
        int ip = i + 1 - ki, jp = j + 1 - kj;
        int off = -1;
        if (ip >= 0 && ip < 24 && jp >= 0 && jp < 24) {
            int a = Arg[b * LPIX + ip * 24 + jp];
            int rr = a / 24 + ki - 1;
            int cc = a % 24 + kj - 1;
            if (rr >= 0 && rr < 24 && cc >= 0 && cc < 24) off = rr * 24 + cc;
        }
        tap[px][t9] = off;
    }
    __syncthreads();
    const int l = l0 + ty;
    const short* Kb = kt + (size_t)b * LPIX * CCH;
    short* dst = x2t + ((size_t)b * LPIX + l) * 4096 + CCH;
    int t[9];
    #pragma unroll
    for (int i = 0; i < 9; ++i) t[i] = tap[ty][i];
    const float inv9 = 1.0f / 9.0f;
    #pragma unroll
    for (int j = 0; j < 8; ++j) {
        int c = (lane + j * 64) * 4;
        float s0 = 0.f, s1 = 0.f, s2 = 0.f, s3 = 0.f;
        #pragma unroll
        for (int t9 = 0; t9 < 9; ++t9) {
            int off = t[t9];
            if (off < 0) continue;
            u16x4 u = *(const u16x4*)(Kb + (size_t)off * CCH + c);
            s0 += bf2f(u.x); s1 += bf2f(u.y); s2 += bf2f(u.z); s3 += bf2f(u.w);
        }
        u16x4 o;
        o.x = f2bf(s0 * inv9); o.y = f2bf(s1 * inv9);
        o.z = f2bf(s2 * inv9); o.w = f2bf(s3 * inv9);
        *(u16x4*)(dst + c) = o;
    }
}

extern "C" void kernel_launch(void* const* d_in, const int* in_sizes, int n_in,
                              void* d_out, int out_size, void* d_ws, size_t ws_size,
                              hipStream_t stream) {
    const float* part_ref = (const float*)d_in[0];
    const float* part_tgt = (const float*)d_in[1];
    const float* wq = (const float*)d_in[2];
    const float* bq = (const float*)d_in[3];
    const float* wk = (const float*)d_in[4];
    const float* bk = (const float*)d_in[5];
    const float* wt = (const float*)d_in[6];
    const float* bt = (const float*)d_in[7];
    float* out = (float*)d_out;

    short* wqb2 = (short*)d_ws;
    short* wtb  = wqb2;                                       // reuse after convs
    short* T1   = wqb2 + (size_t)2 * CCH * CCH;
    short* kt   = T1 + (size_t)2 * NB * LPIX * CCH;
    short* x2t  = kt + (size_t)NB * LPIX * CCH;
    float* Mpart = (float*)T1;                                // aliases T1 (dead by gram time)
    float* nk    = (float*)(x2t + (size_t)NB * LPIX * 4096);
    float* nq    = nk + NB * LPIX;
    float* Sbuf  = nq + NB * LPIX;
    int*   Arg   = (int*)(Sbuf + NB * LPIX);
    float* Pv    = (float*)(Arg + NB * LPIX);                 // 24*NB*LPIX
    int*   Pi    = (int*)(Pv + (size_t)24 * NB * LPIX);

    hipMemsetAsync(nk, 0, 2 * NB * LPIX * sizeof(float), stream);  // nk|nq contiguous

    wcast2_k<<<dim3(4096, 2), 256, 0, stream>>>(wq, wk, wqb2);
    tcast_k<<<dim3(18, 64, 8), dim3(32, 8), 0, stream>>>(part_tgt, part_ref, T1);

    // q -> x2t[:, :, 0:2048]; k -> kt; fused channel-norm atomics (576 blocks, swizzled)
    conv_k<<<576, 256, 0, stream>>>(T1, wqb2, bq, bk, x2t, kt, nq, nk);

    // gram split-K2 -> Mpart (648 blocks)
    gram_k<<<dim3(9, 9, 8), 256, 0, stream>>>(kt, x2t, Mpart);

    argmax1_k<<<dim3(9, 24, NB), dim3(64, 4), 0, stream>>>(Mpart, nk, Pv, Pi);
    argmax2_k<<<9, 256, 0, stream>>>(Pv, Pi, nq, Sbuf, Arg);

    gather_k<<<576, dim3(64, 4), 0, stream>>>(kt, Arg, x2t);

    wcast_k<<<8192, 256, 0, stream>>>(wt, wtb);
    // final fused conv (288 blocks: 16 o-tiles x 18 bl-tiles, swizzled)
    fin_k<<<288, 256, 0, stream>>>(wtb, x2t, bt, Sbuf, part_tgt, out);
}

// Round 5
// 370.282 us; speedup vs baseline: 1.1553x; 1.0189x over previous
//
#include <hip/hip_runtime.h>
#include <cstddef>
#include <cstdint>

#define LPIX 576
#define CCH  2048
#define NB   4

typedef __attribute__((ext_vector_type(8))) short short8;
typedef __attribute__((ext_vector_type(4))) float f32x4;
typedef __attribute__((ext_vector_type(4))) unsigned short u16x4;

__device__ __forceinline__ unsigned short f2bf(float f) {
    uint32_t u = __builtin_bit_cast(uint32_t, f);
    u += 0x7fff + ((u >> 16) & 1);          // round-to-nearest-even
    return (unsigned short)(u >> 16);
}
__device__ __forceinline__ float bf2f(unsigned short s) {
    return __builtin_bit_cast(float, (uint32_t)s << 16);
}

__device__ __forceinline__ void gload_lds16(const void* g, void* l) {
    __builtin_amdgcn_global_load_lds((const __attribute__((address_space(1))) void*)g,
                                     (__attribute__((address_space(3))) void*)l, 16, 0, 0);
}

// ---------------- MFMA K-loop, BK=64 twin 32-k panels ----------------
template<int BM, int BN>
__device__ __forceinline__ void mm_core64(
    const short* __restrict__ Ab, int lda,
    const short* __restrict__ Bb, int ldb,
    int k0, int kend, short* As, short* Bs,
    int m0, int n0, f32x4 (&acc)[BM/32][BN/32])
{
    const int tid  = threadIdx.x;
    const int lane = tid & 63;
    const int w    = tid >> 6;
    const int wm = (w & 1) * (BM / 2);
    const int wn = (w >> 1) * (BN / 2);
    const int l15 = lane & 15;
    const int k8  = (lane >> 4) * 8;
    const int r   = tid >> 2;          // 0..63
    const int kk  = (tid & 3) * 8;     // 0,8,16,24 within a 32-k panel

    const short* Aptr[BM / 32]; short* Alds[BM / 32];
    #pragma unroll
    for (int u = 0; u < BM / 32; ++u) {
        const int p = u & 1, g = u >> 1;
        Aptr[u] = Ab + (size_t)(m0 + g * 64 + r) * lda + p * 32 + kk;
        Alds[u] = As + p * BM * 32 + g * 2048 + tid * 8;
    }
    const short* Bptr[BN / 32]; short* Blds[BN / 32];
    #pragma unroll
    for (int u = 0; u < BN / 32; ++u) {
        const int p = u & 1, g = u >> 1;
        Bptr[u] = Bb + (size_t)(n0 + g * 64 + r) * ldb + p * 32 + kk;
        Blds[u] = Bs + p * BN * 32 + g * 2048 + tid * 8;
    }

    for (int c0 = k0; c0 < kend; c0 += 64) {
        #pragma unroll
        for (int u = 0; u < BM / 32; ++u) gload_lds16(Aptr[u] + c0, Alds[u]);
        #pragma unroll
        for (int u = 0; u < BN / 32; ++u) gload_lds16(Bptr[u] + c0, Blds[u]);
        __syncthreads();
        #pragma unroll
        for (int s = 0; s < 2; ++s) {
            short8 fa[BM / 32], fb[BN / 32];
            #pragma unroll
            for (int i = 0; i < BM / 32; ++i)
                fa[i] = *(const short8*)(As + s * BM * 32 + (wm + i * 16 + l15) * 32 + k8);
            #pragma unroll
            for (int j = 0; j < BN / 32; ++j)
                fb[j] = *(const short8*)(Bs + s * BN * 32 + (wn + j * 16 + l15) * 32 + k8);
            #pragma unroll
            for (int i = 0; i < BM / 32; ++i)
                #pragma unroll
                for (int j = 0; j < BN / 32; ++j)
                    acc[i][j] = __builtin_amdgcn_mfma_f32_16x16x32_bf16(fa[i], fb[j], acc[i][j], 0, 0, 0);
        }
        __syncthreads();
    }
}

// ---------------- both conv weight casts in one dispatch ----------------
__global__ __launch_bounds__(256) void wcast2_k(const float* __restrict__ wq,
                                                const float* __restrict__ wk,
                                                short* __restrict__ Wb) {
    const float* W = blockIdx.y ? wk : wq;
    short* D = Wb + (size_t)blockIdx.y * CCH * CCH;
    int i = (blockIdx.x * 256 + threadIdx.x) * 4;
    float4 v = *(const float4*)(W + i);
    u16x4 u;
    u.x = f2bf(v.x); u.y = f2bf(v.y); u.z = f2bf(v.z); u.w = f2bf(v.w);
    *(u16x4*)(D + i) = u;
}

__global__ __launch_bounds__(256) void wcast_k(const float* __restrict__ W,
                                               short* __restrict__ Wb) {
    int i = (blockIdx.x * 256 + threadIdx.x) * 4;
    float4 v = *(const float4*)(W + i);
    u16x4 u;
    u.x = f2bf(v.x); u.y = f2bf(v.y); u.z = f2bf(v.z); u.w = f2bf(v.w);
    *(u16x4*)(Wb + i) = u;
}

// ---------------- merged transpose-cast: tgt & ref [b][c][l] fp32 -> T1[which][b][l][c] bf16 ----
__global__ __launch_bounds__(256) void tcast_k(const float* __restrict__ tgt,
                                               const float* __restrict__ ref,
                                               short* __restrict__ T1) {
    __shared__ float tile[32][33];
    const int z = blockIdx.z;
    const int b = z & 3, which = z >> 2;
    const float* X = (which ? ref : tgt) + (size_t)b * CCH * LPIX;
    const int c0 = blockIdx.y * 32;
    const int l0 = blockIdx.x * 32;
    const int tx = threadIdx.x, ty = threadIdx.y;
    #pragma unroll
    for (int j = 0; j < 4; ++j)
        tile[ty + j * 8][tx] = X[(size_t)(c0 + ty + j * 8) * LPIX + l0 + tx];
    __syncthreads();
    short* D = T1 + ((size_t)(which * NB + b) * LPIX) * CCH;
    #pragma unroll
    for (int j = 0; j < 4; ++j)
        D[(size_t)(l0 + ty + j * 8) * CCH + c0 + tx] = (short)f2bf(tile[tx][ty + j * 8]);
}

// ---------------- merged q/k conv, XCD-swizzled, fused channel-sqnorm atomics ----------
// 1D grid 1152: xcd=id&7 owns 4 weight slabs (2 MB, L2-resident)
__global__ __launch_bounds__(256) void conv_k(
    const short* __restrict__ T1, const short* __restrict__ Wb,
    const float* __restrict__ bq, const float* __restrict__ bk,
    short* __restrict__ x2t, short* __restrict__ kt,
    float* __restrict__ nq, float* __restrict__ nk)
{
    __shared__ short As[64 * 64];
    __shared__ short Bs[128 * 64];
    const int id = blockIdx.x;
    const int xcd = id & 7, slot = id >> 3;          // slot 0..143
    const int sid = xcd * 4 + slot / 36;             // weight slab 0..31
    const int r36 = slot % 36;
    const int which = sid >> 4;
    const int m0 = (r36 % 9) * 64;                   // l
    const int n0 = (sid & 15) * 128;                 // o
    const int b  = r36 / 9;
    const short* Ab = T1 + (size_t)(which * NB + b) * LPIX * CCH;
    const short* Bb = Wb + (size_t)which * CCH * CCH;
    const float* bias = which ? bk : bq;
    short* Yb = which ? (kt + (size_t)b * LPIX * CCH) : (x2t + (size_t)b * LPIX * 4096);
    float* Nb = (which ? nk : nq) + b * LPIX;
    const int ldy = which ? CCH : 4096;
    f32x4 acc[2][4] = {};
    mm_core64<64, 128>(Ab, CCH, Bb, CCH, 0, CCH, As, Bs, m0, n0, acc);
    const int lane = threadIdx.x & 63, w = threadIdx.x >> 6;
    const int wm = (w & 1) * 32, wn = (w >> 1) * 64;
    const int l15 = lane & 15, quad = lane >> 4;
    float pv[2][4] = {};
    #pragma unroll
    for (int i = 0; i < 2; ++i)
        #pragma unroll
        for (int j = 0; j < 4; ++j) {
            const int gn = n0 + wn + j * 16 + l15;
            const float bi = bias[gn];
            #pragma unroll
            for (int r = 0; r < 4; ++r) {
                const int gm = m0 + wm + i * 16 + quad * 4 + r;
                float v = acc[i][j][r] + bi;
                pv[i][r] += v * v;
                Yb[(size_t)gm * ldy + gn] = (short)f2bf(v);
            }
        }
    // reduce pv over the 16 lanes sharing (i,quad,r), then atomic into norm buffer
    #pragma unroll
    for (int i = 0; i < 2; ++i)
        #pragma unroll
        for (int r = 0; r < 4; ++r) {
            float s = pv[i][r];
            #pragma unroll
            for (int m = 1; m < 16; m <<= 1) s += __shfl_xor(s, m);
            if (l15 == 0) {
                const int gm = m0 + wm + i * 16 + quad * 4 + r;
                atomicAdd(&Nb[gm], s);
            }
        }
}

// ---------------- gram with split-K2: M_part[kc][b][lr][lt], 64x64 tiles ----------------
__global__ __launch_bounds__(256) void gram_k(
    const short* __restrict__ kt, const short* __restrict__ x2t,
    float* __restrict__ Mpart)
{
    __shared__ short As[64 * 64];
    __shared__ short Bs[64 * 64];
    const int z = blockIdx.z;
    const int b = z >> 1, kc = z & 1;
    const short* Ab = kt + (size_t)b * LPIX * CCH;
    const short* Bb = x2t + (size_t)b * LPIX * 4096;
    const int m0 = blockIdx.y * 64;   // lr
    const int n0 = blockIdx.x * 64;   // lt
    f32x4 acc[2][2] = {};
    mm_core64<64, 64>(Ab, CCH, Bb, 4096, kc * 1024, kc * 1024 + 1024, As, Bs, m0, n0, acc);
    float* Mb = Mpart + (size_t)(kc * NB + b) * LPIX * LPIX;
    const int lane = threadIdx.x & 63, w = threadIdx.x >> 6;
    const int wm = (w & 1) * 32, wn = (w >> 1) * 32;
    const int l15 = lane & 15, quad = lane >> 4;
    #pragma unroll
    for (int i = 0; i < 2; ++i)
        #pragma unroll
        for (int j = 0; j < 2; ++j) {
            const int gn = n0 + wn + j * 16 + l15;
            #pragma unroll
            for (int r = 0; r < 4; ++r) {
                const int gm = m0 + wm + i * 16 + quad * 4 + r;
                Mb[(size_t)gm * LPIX + gn] = acc[i][j][r];
            }
        }
}

// ---------------- final: 128(o) x 64(l) x split-K2, atomic accumulate ----------
// 1152 blocks (vs round-0's 576 @ K=4096): same <128,64> core & wave geometry, half K
// per block -> 4.5 blocks/CU (the density where conv_k is fastest). The two k-half
// partials combine via atomicAdd (exactly 2 commutative f32 adds per address ->
// deterministic); out is zeroed by stream memset. Epilogue folded so that
// sum = (acc0+acc1+bt)*S + PT. xcd owns 2 o-tiles x full K (2 MB weights, L2-resident).
__global__ __launch_bounds__(256) void fin_k(
    const short* __restrict__ wtb, const short* __restrict__ x2t,
    const float* __restrict__ bt, const float* __restrict__ S,
    const float* __restrict__ PT, float* __restrict__ out)
{
    __shared__ short As[128 * 64];
    __shared__ short Bs[64 * 64];
    const int id = blockIdx.x;
    const int xcd = id & 7, slot = id >> 3;          // slot 0..143
    const int sid = xcd * 4 + slot / 36;             // 0..31
    const int o2 = sid >> 1, kc = sid & 1;           // o-tile 0..15, k-half 0..1
    const int r36 = slot % 36;                       // 9 l-tiles x 4 b
    const int m0 = o2 * 128;                         // o
    const int n0 = (r36 % 9) * 64;                   // l
    const int b  = r36 / 9;
    const short* Bb = x2t + (size_t)b * LPIX * 4096;
    f32x4 acc[4][2] = {};
    mm_core64<128, 64>(wtb, 4096, Bb, 4096, kc * 2048, kc * 2048 + 2048, As, Bs, m0, n0, acc);
    const int lane = threadIdx.x & 63, w = threadIdx.x >> 6;
    const int wm = (w & 1) * 64, wn = (w >> 1) * 32;
    const int l15 = lane & 15, quad = lane >> 4;
    #pragma unroll
    for (int i = 0; i < 4; ++i)
        #pragma unroll
        for (int j = 0; j < 2; ++j) {
            const int gn = n0 + wn + j * 16 + l15;
            const float sv = S[b * LPIX + gn];
            #pragma unroll
            for (int r = 0; r < 4; ++r) {
                const int gm = m0 + wm + i * 16 + quad * 4 + r;
                const size_t idx = ((size_t)b * CCH + gm) * LPIX + gn;
                float v = kc ? (acc[i][j][r] + bt[gm]) * sv + PT[idx]
                             : acc[i][j][r] * sv;
                atomicAdd(&out[idx], v);
            }
        }
}

// ---------------- stage 1: fused 3x3-box invNk + 9-tap aggregation + chunk argmax ----
__global__ __launch_bounds__(256) void argmax1_k(
    const float* __restrict__ Mpart, const float* __restrict__ nk,
    float* __restrict__ Pv, int* __restrict__ Pi)
{
    const int b   = blockIdx.z;
    const int lrb = blockIdx.y;                 // ir row 0..23
    const int tx = threadIdx.x, ty = threadIdx.y;
    const int tid = ty * 64 + tx;
    __shared__ float invNkS[24];
    if (tid < 24) {
        const int jr = tid;
        float s = 0.f;
        #pragma unroll
        for (int di = -1; di <= 1; ++di) {
            const int ii = lrb + di;
            if ((unsigned)ii > 23u) continue;
            #pragma unroll
            for (int dj = -1; dj <= 1; ++dj) {
                const int jj = jr + dj;
                if ((unsigned)jj > 23u) continue;
                s += nk[b * LPIX + ii * 24 + jj];
            }
        }
        invNkS[jr] = 1.0f / fmaxf(sqrtf(s), 1e-12f);
    }
    __syncthreads();
    const int lt = blockIdx.x * 64 + tx;
    const int it = lt / 24, jt = lt % 24;
    const float* Mb0 = Mpart + (size_t)b * LPIX * LPIX;
    const float* Mb1 = Mpart + (size_t)(NB + b) * LPIX * LPIX;
    float best = -1e30f; int bidx = 0;
    #pragma unroll
    for (int i = 0; i < 6; ++i) {
        const int jr = ty + i * 4;
        const int lr = lrb * 24 + jr;
        const int base = lr * LPIX + lt;
        float g = 0.f;
        #pragma unroll
        for (int di = -1; di <= 1; ++di) {
            if ((unsigned)(lrb + di) > 23u || (unsigned)(it + di) > 23u) continue;
            #pragma unroll
            for (int dj = -1; dj <= 1; ++dj) {
                if ((unsigned)(jr + dj) > 23u || (unsigned)(jt + dj) > 23u) continue;
                const int o = base + (di * 24 + dj) * (LPIX + 1);
                g += Mb0[o] + Mb1[o];
            }
        }
        float v = g * invNkS[jr];
        if (v > best) { best = v; bidx = lr; }
    }
    __shared__ float rv[4][64];
    __shared__ int   ri[4][64];
    rv[ty][tx] = best; ri[ty][tx] = bidx;
    __syncthreads();
    if (ty == 0) {
        #pragma unroll
        for (int y = 1; y < 4; ++y) {
            float v = rv[y][tx]; int id = ri[y][tx];
            if (v > best || (v == best && id < bidx)) { best = v; bidx = id; }
        }
        Pv[((size_t)b * 24 + lrb) * LPIX + lt] = best;
        Pi[((size_t)b * 24 + lrb) * LPIX + lt] = bidx;
    }
}

// ---------------- stage 2: fold 24 partials, fused invNq ----------------
__global__ __launch_bounds__(256) void argmax2_k(
    const float* __restrict__ Pv, const int* __restrict__ Pi,
    const float* __restrict__ nq,
    float* __restrict__ S, int* __restrict__ Arg)
{
    int idx = blockIdx.x * 256 + threadIdx.x;
    if (idx >= NB * LPIX) return;
    int b = idx / LPIX, lt = idx % LPIX;
    int it = lt / 24, jt = lt % 24;
    float s = 0.f;
    #pragma unroll
    for (int di = -1; di <= 1; ++di) {
        const int ii = it + di;
        if ((unsigned)ii > 23u) continue;
        #pragma unroll
        for (int dj = -1; dj <= 1; ++dj) {
            const int jj = jt + dj;
            if ((unsigned)jj > 23u) continue;
            s += nq[b * LPIX + ii * 24 + jj];
        }
    }
    const float invNq = 1.0f / fmaxf(sqrtf(s), 1e-12f);
    float best = -1e30f; int bidx = 0;
    #pragma unroll
    for (int c = 0; c < 24; ++c) {
        float v = Pv[((size_t)b * 24 + c) * LPIX + lt];
        int  id = Pi[((size_t)b * 24 + c) * LPIX + lt];
        if (v > best || (v == best && id < bidx)) { best = v; bidx = id; }
    }
    S[idx]   = best * invNq;
    Arg[idx] = bidx;
}

// ---------------- gather best ref patches + fold (/9), XCD-swizzled ----------------
// 1D grid 576: XCD pair owns one b (kt[b]=2.36 MB L2-resident)
__global__ __launch_bounds__(256) void gather_k(
    const short* __restrict__ kt, const int* __restrict__ Arg,
    short* __restrict__ x2t)
{
    const int id = blockIdx.x;
    const int xcd = id & 7, slot = id >> 3;          // slot 0..71
    const int b  = xcd >> 1;
    const int l0 = ((xcd & 1) * 72 + slot) * 4;
    const int lane = threadIdx.x, ty = threadIdx.y;
    const int tid = ty * 64 + lane;
    __shared__ int tap[4][9];
    if (tid < 36) {
        int px = tid / 9, t9 = tid % 9;
        int l = l0 + px;
        int i = l / 24, j = l % 24;
        int ki = t9 / 3, kj = t9 % 3;
        int ip = i + 1 - ki, jp = j + 1 - kj;
        int off = -1;
        if (ip >= 0 && ip < 24 && jp >= 0 && jp < 24) {
            int a = Arg[b * LPIX + ip * 24 + jp];
            int rr = a / 24 + ki - 1;
            int cc = a % 24 + kj - 1;
            if (rr >= 0 && rr < 24 && cc >= 0 && cc < 24) off = rr * 24 + cc;
        }
        tap[px][t9] = off;
    }
    __syncthreads();
    const int l = l0 + ty;
    const short* Kb = kt + (size_t)b * LPIX * CCH;
    short* dst = x2t + ((size_t)b * LPIX + l) * 4096 + CCH;
    int t[9];
    #pragma unroll
    for (int i = 0; i < 9; ++i) t[i] = tap[ty][i];
    const float inv9 = 1.0f / 9.0f;
    #pragma unroll
    for (int j = 0; j < 8; ++j) {
        int c = (lane + j * 64) * 4;
        float s0 = 0.f, s1 = 0.f, s2 = 0.f, s3 = 0.f;
        #pragma unroll
        for (int t9 = 0; t9 < 9; ++t9) {
            int off = t[t9];
            if (off < 0) continue;
            u16x4 u = *(const u16x4*)(Kb + (size_t)off * CCH + c);
            s0 += bf2f(u.x); s1 += bf2f(u.y); s2 += bf2f(u.z); s3 += bf2f(u.w);
        }
        u16x4 o;
        o.x = f2bf(s0 * inv9); o.y = f2bf(s1 * inv9);
        o.z = f2bf(s2 * inv9); o.w = f2bf(s3 * inv9);
        *(u16x4*)(dst + c) = o;
    }
}

extern "C" void kernel_launch(void* const* d_in, const int* in_sizes, int n_in,
                              void* d_out, int out_size, void* d_ws, size_t ws_size,
                              hipStream_t stream) {
    const float* part_ref = (const float*)d_in[0];
    const float* part_tgt = (const float*)d_in[1];
    const float* wq = (const float*)d_in[2];
    const float* bq = (const float*)d_in[3];
    const float* wk = (const float*)d_in[4];
    const float* bk = (const float*)d_in[5];
    const float* wt = (const float*)d_in[6];
    const float* bt = (const float*)d_in[7];
    float* out = (float*)d_out;

    short* wqb2 = (short*)d_ws;
    short* wtb  = wqb2;                                       // reuse after convs
    short* T1   = wqb2 + (size_t)2 * CCH * CCH;
    short* kt   = T1 + (size_t)2 * NB * LPIX * CCH;
    short* x2t  = kt + (size_t)NB * LPIX * CCH;
    float* Mpart = (float*)T1;                                // aliases T1 (dead by gram time)
    float* nk    = (float*)(x2t + (size_t)NB * LPIX * 4096);
    float* nq    = nk + NB * LPIX;
    float* Sbuf  = nq + NB * LPIX;
    int*   Arg   = (int*)(Sbuf + NB * LPIX);
    float* Pv    = (float*)(Arg + NB * LPIX);                 // 24*NB*LPIX
    int*   Pi    = (int*)(Pv + (size_t)24 * NB * LPIX);

    hipMemsetAsync(nk, 0, 2 * NB * LPIX * sizeof(float), stream);  // nk|nq contiguous
    hipMemsetAsync(out, 0, (size_t)NB * CCH * LPIX * sizeof(float), stream);  // fin accumulates

    wcast2_k<<<dim3(4096, 2), 256, 0, stream>>>(wq, wk, wqb2);
    tcast_k<<<dim3(18, 64, 8), dim3(32, 8), 0, stream>>>(part_tgt, part_ref, T1);

    // q -> x2t[:, :, 0:2048]; k -> kt; fused channel-norm atomics (1152 blocks, swizzled)
    conv_k<<<1152, 256, 0, stream>>>(T1, wqb2, bq, bk, x2t, kt, nq, nk);

    // gram split-K2 -> Mpart (648 blocks)
    gram_k<<<dim3(9, 9, 8), 256, 0, stream>>>(kt, x2t, Mpart);

    argmax1_k<<<dim3(9, 24, NB), dim3(64, 4), 0, stream>>>(Mpart, nk, Pv, Pi);
    argmax2_k<<<9, 256, 0, stream>>>(Pv, Pi, nq, Sbuf, Arg);

    gather_k<<<576, dim3(64, 4), 0, stream>>>(kt, Arg, x2t);

    wcast_k<<<8192, 256, 0, stream>>>(wt, wtb);
    // final fused conv, split-K2 atomic accumulate (1152 blocks, swizzled)
    fin_k<<<1152, 256, 0, stream>>>(wtb, x2t, bt, Sbuf, part_tgt, out);
}